// Round 3
// baseline (56986.700 us; speedup 1.0000x reference)
//
#include <hip/hip_runtime.h>

// Persistent-LSTM MI355X — Round 9: 128 blocks x 1024 threads, designated
// poller + LDS fan-out. R7 (fused words) and R8 (burn poll, barrier-free
// publish) both regressed; R6's publish ordering and s_sleep polls are kept
// verbatim. R9 attacks the real cost: coherence-point CONTENTION. R6 had
// 2048 poller-waves hammering 16 tag lines (256 pollers/line-pair, ~100cy
// retry) — tag writes and detection reads queue behind the poll storm.
// R9: (a) halve the parties: 128 blocks x 16 waves (same 2048 waves total,
// weights stay register-resident; ~104 VGPR -> 4 waves/SIMD -> 1 block/CU);
// (b) ONE poller wave per block (128 pollers total, 2 coalesced loads per
// retry + s_sleep(1)) raises an LDS flag; 15 waves spin on LDS (free).
// Poll fabric traffic drops ~16x; tag stores and data lines halve.
//
// Block b owns units [16b,16b+16); wave wv computes unit j=16b+wv; lane ln
// holds W_hh chunks {4(ln+64k)} in VGPRs (128 floats/lane, unchanged).
// Publish (R6-validated): ln==0 h-store -> __syncthreads (drains vmcnt) ->
// tid0 tag store. WAR invariant unchanged: publishing h_{t+1} requires
// flag(t) = all tags >= t, which implies every block finished reading
// h_{t-1} (staged before its own tag-t store).

#define H      2048
#define TSTEPS 8192
#define FEAT   128
#define NBLK   128
#define NTHR   1024
#define UPB    16   // units (= waves) per block

typedef float vf4 __attribute__((ext_vector_type(4)));
typedef float vf2 __attribute__((ext_vector_type(2)));
typedef unsigned long long u64;
typedef unsigned int u32;

__device__ __forceinline__ float sigm(float xv) {
  return __builtin_amdgcn_rcpf(1.0f + __expf(-xv));
}
__device__ __forceinline__ float tanh_(float xv) {
  return 1.0f - 2.0f * __builtin_amdgcn_rcpf(__expf(2.0f * xv) + 1.0f);
}

__device__ __forceinline__ u64 aload64(const u64* p) {
  return __hip_atomic_load(p, __ATOMIC_RELAXED, __HIP_MEMORY_SCOPE_AGENT);
}
__device__ __forceinline__ u32 aload32(const u32* p) {
  return __hip_atomic_load(p, __ATOMIC_RELAXED, __HIP_MEMORY_SCOPE_AGENT);
}
__device__ __forceinline__ void astoref(float* p, float v) {
  __hip_atomic_store(p, v, __ATOMIC_RELAXED, __HIP_MEMORY_SCOPE_AGENT);
}
__device__ __forceinline__ void astoreu(u32* p, u32 v) {
  __hip_atomic_store(p, v, __ATOMIC_RELAXED, __HIP_MEMORY_SCOPE_AGENT);
}
__device__ __forceinline__ void flag_store(int* f, int v) {
  __hip_atomic_store(f, v, __ATOMIC_RELAXED, __HIP_MEMORY_SCOPE_WORKGROUP);
}
__device__ __forceinline__ int flag_load(const int* f) {
  return __hip_atomic_load(f, __ATOMIC_RELAXED, __HIP_MEMORY_SCOPE_WORKGROUP);
}

#define DECLG(g) vf4 w##g##_0, w##g##_1, w##g##_2, w##g##_3, \
                     w##g##_4, w##g##_5, w##g##_6, w##g##_7; \
                 vf2 wih##g; float bias##g; float acc##g;

#define LOADG(g) { \
  const int row_ = (g) * H + j; \
  const float* wr_ = W_hh + (long)row_ * H; \
  w##g##_0 = *(const vf4*)(wr_ + 4*(ln      )); \
  w##g##_1 = *(const vf4*)(wr_ + 4*(ln +  64)); \
  w##g##_2 = *(const vf4*)(wr_ + 4*(ln + 128)); \
  w##g##_3 = *(const vf4*)(wr_ + 4*(ln + 192)); \
  w##g##_4 = *(const vf4*)(wr_ + 4*(ln + 256)); \
  w##g##_5 = *(const vf4*)(wr_ + 4*(ln + 320)); \
  w##g##_6 = *(const vf4*)(wr_ + 4*(ln + 384)); \
  w##g##_7 = *(const vf4*)(wr_ + 4*(ln + 448)); \
  wih##g  = *(const vf2*)(W_ih + (long)row_ * FEAT + 2*ln); \
  bias##g = b_ih[row_] + b_hh[row_]; }

// Opaque pin: weights become non-rematerializable (cannot re-sink into loop).
#define PIN(g) asm volatile("" : \
  "+v"(w##g##_0), "+v"(w##g##_1), "+v"(w##g##_2), "+v"(w##g##_3), \
  "+v"(w##g##_4), "+v"(w##g##_5), "+v"(w##g##_6), "+v"(w##g##_7), \
  "+v"(wih##g), "+v"(bias##g));

#define LDSREAD(k, ldsrow) \
  const vf4 hv##k = *(const vf4*)&(ldsrow)[4*(ln + 64*(k))];

#define FMA_G(g, c) \
  acc##g = __builtin_fmaf(w##g##_##c.x, h4_.x, acc##g); \
  acc##g = __builtin_fmaf(w##g##_##c.y, h4_.y, acc##g); \
  acc##g = __builtin_fmaf(w##g##_##c.z, h4_.z, acc##g); \
  acc##g = __builtin_fmaf(w##g##_##c.w, h4_.w, acc##g);

#define FMA_C(c) { const vf4 h4_ = hv##c; \
  FMA_G(0, c) FMA_G(1, c) FMA_G(2, c) FMA_G(3, c) }

#define REDUCE(g) { float a_ = acc##g; \
  a_ += __shfl_xor(a_, 1);  a_ += __shfl_xor(a_, 2);  a_ += __shfl_xor(a_, 4); \
  a_ += __shfl_xor(a_, 8);  a_ += __shfl_xor(a_, 16); a_ += __shfl_xor(a_, 32); \
  acc##g = a_ + bias##g; }

// Gate: wave 0 polls all 128 block tags (slots[ln], slots[64+ln]; 2 coalesced
// loads per retry, s_sleep(1) backoff — 128 pollers TOTAL device-wide), then
// raises the LDS flag; other waves spin on LDS (no fabric traffic). Signed
// compare keeps 0xAA poison inert.
__device__ __forceinline__ void gate_wait(const u32* __restrict__ slots,
                                          int tgt, int wv, int ln, int* flag) {
  if (wv == 0) {
    const u32* sp = slots + ln;
    int v0 = (int)aload32(sp);
    int v1 = (int)aload32(sp + 64);
    while (!__all((v0 >= tgt) & (v1 >= tgt))) {
      __builtin_amdgcn_s_sleep(1);
      if (v0 < tgt) v0 = (int)aload32(sp);
      if (v1 < tgt) v1 = (int)aload32(sp + 64);
    }
    if (ln == 0) flag_store(flag, tgt);
  } else {
    while (flag_load(flag) < tgt) { }
  }
}

// One-shot read of this wave's 128-float h-slice (2 floats/lane, one u64
// agent-scope load) and deposit into LDS.
__device__ __forceinline__ void stage_slice(const float* __restrict__ hsrc,
                                            float* __restrict__ ldsrow,
                                            int wv, int ln) {
  const int base = wv * 128 + 2 * ln;
  const u64 d = aload64((const u64*)(hsrc + base));
  vf2 hv;
  hv.x = __uint_as_float((u32)d);
  hv.y = __uint_as_float((u32)(d >> 32));
  *(vf2*)&ldsrow[base] = hv;
}

__global__ __launch_bounds__(NTHR, 4)
void lstm_persist(const float* __restrict__ x,
                  const float* __restrict__ W_ih,
                  const float* __restrict__ W_hh,
                  const float* __restrict__ b_ih,
                  const float* __restrict__ b_hh,
                  const float* __restrict__ W_lin,
                  const float* __restrict__ b_lin,
                  const float* __restrict__ W_out,
                  const float* __restrict__ b_out,
                  float* __restrict__ out,
                  float* __restrict__ ws)
{
  const int tid = threadIdx.x;
  const int b   = blockIdx.x;
  const int wv  = tid >> 6;
  const int ln  = tid & 63;

  float* hbuf0 = ws;            // [2048] h for even t
  float* hbuf1 = ws + H;        // [2048] h for odd t; reused for ylin
  u32*   slots = (u32*)(ws + 2 * H);   // [128] per-block step counters, 512B

  __shared__ __align__(16) float h_lds[2][H];
  __shared__ int flag;          // monotonic step flag (LDS fan-out)

  // h_0 = 0: zero parity-0 LDS row (1024 threads x 8B)
  *(vf2*)&h_lds[0][2 * tid] = (vf2)(0.0f);
  if (tid == 0) flag = 0;

  // ---- persistent weights: load then pin ----
  const int j = b * UPB + wv;
  DECLG(0) DECLG(1) DECLG(2) DECLG(3)
  LOADG(0) LOADG(1) LOADG(2) LOADG(3)
  PIN(0) PIN(1) PIN(2) PIN(3)

  __syncthreads();

  float cst = 0.0f;

  #pragma unroll 1
  for (int t = 0; t < TSTEPS; ++t) {
    const vf2 xr = *(const vf2*)(x + (long)t * FEAT + 2 * ln);
    float* ldsrow = h_lds[t & 1];

    if (t > 0) {
      gate_wait(slots, t, wv, ln, &flag);
      stage_slice((t & 1) ? hbuf1 : hbuf0, ldsrow, wv, ln);
    }
    __syncthreads();  // all slices staged before any LDS read; also guards
                      // 2-ahead LDS row reuse (R6-validated structure)

    LDSREAD(0, ldsrow) LDSREAD(1, ldsrow) LDSREAD(2, ldsrow) LDSREAD(3, ldsrow)
    LDSREAD(4, ldsrow) LDSREAD(5, ldsrow) LDSREAD(6, ldsrow) LDSREAD(7, ldsrow)

    acc0 = wih0.x * xr.x + wih0.y * xr.y;
    acc1 = wih1.x * xr.x + wih1.y * xr.y;
    acc2 = wih2.x * xr.x + wih2.y * xr.y;
    acc3 = wih3.x * xr.x + wih3.y * xr.y;

    FMA_C(0) FMA_C(1) FMA_C(2) FMA_C(3)
    FMA_C(4) FMA_C(5) FMA_C(6) FMA_C(7)

    REDUCE(0) REDUCE(1) REDUCE(2) REDUCE(3)

    // gate order [i, f, g, o]
    const float iv = sigm(acc0);
    const float fv = sigm(acc1);
    const float gv = tanh_(acc2);
    const float ov = sigm(acc3);
    cst = fv * cst + iv * gv;
    const float hval = ov * tanh_(cst);

    // publish h_{t+1} (R6-validated ordering): one plain store per wave;
    // __syncthreads drains vmcnt(0) per wave -> all 16 h stores visible
    // BEFORE the tag store below. Block's slice = 16 floats = ONE line.
    if (ln == 0)
      astoref((((t + 1) & 1) ? hbuf1 : hbuf0) + j, hval);
    __syncthreads();
    if (tid == 0)
      astoreu(slots + b, (u32)(t + 1));
  }

  // ---- head phase 1: ylin[j] = b_lin[j] + dot(W_lin[j,:], h_final) ----
  // h_final = h_8192, parity 0; all tags reach TSTEPS after the loop.
  {
    float* ldsrow = h_lds[0];
    gate_wait(slots, TSTEPS, wv, ln, &flag);
    stage_slice(hbuf0, ldsrow, wv, ln);
    __syncthreads();

    float a0 = 0.0f;
    const float* wl = W_lin + (long)j * H;
    #pragma unroll
    for (int k = 0; k < 8; ++k) {
      const vf4 h4 = *(const vf4*)&ldsrow[4 * (ln + 64 * k)];
      const vf4 u  = *(const vf4*)(wl + 4 * (ln + 64 * k));
      a0 += u.x * h4.x + u.y * h4.y + u.z * h4.z + u.w * h4.w;
    }
    a0 += __shfl_xor(a0, 1);  a0 += __shfl_xor(a0, 2);  a0 += __shfl_xor(a0, 4);
    a0 += __shfl_xor(a0, 8);  a0 += __shfl_xor(a0, 16); a0 += __shfl_xor(a0, 32);

    if (ln == 0)
      astoref(hbuf1 + j, a0 + b_lin[j]);   // ylin lives in hbuf1 (safe: all
                                           // blocks are past reading h_8191)
    __syncthreads();
    if (tid == 0)
      astoreu(slots + b, (u32)(TSTEPS + 1));
  }

  // ---- head phase 2: y = ylin @ W_out.T + b_out (block 0, wave 0) ----
  if (b == 0 && wv == 0) {
    const u32* sp = slots + ln;
    int v0 = (int)aload32(sp);
    int v1 = (int)aload32(sp + 64);
    const int tgt = TSTEPS + 1;
    while (!__all((v0 >= tgt) & (v1 >= tgt))) {
      __builtin_amdgcn_s_sleep(1);
      if (v0 < tgt) v0 = (int)aload32(sp);
      if (v1 < tgt) v1 = (int)aload32(sp + 64);
    }
    float p0 = 0.0f, p1 = 0.0f;
    #pragma unroll
    for (int k = 0; k < 16; ++k) {
      const u64 d  = aload64((const u64*)hbuf1 + ln + 64 * k);
      const int c  = 2 * (ln + 64 * k);
      const float ylo = __uint_as_float((u32)d);
      const float yhi = __uint_as_float((u32)(d >> 32));
      p0 = __builtin_fmaf(W_out[c],         ylo, p0);
      p0 = __builtin_fmaf(W_out[c + 1],     yhi, p0);
      p1 = __builtin_fmaf(W_out[H + c],     ylo, p1);
      p1 = __builtin_fmaf(W_out[H + c + 1], yhi, p1);
    }
    p0 += __shfl_xor(p0, 1);  p0 += __shfl_xor(p0, 2);  p0 += __shfl_xor(p0, 4);
    p0 += __shfl_xor(p0, 8);  p0 += __shfl_xor(p0, 16); p0 += __shfl_xor(p0, 32);
    p1 += __shfl_xor(p1, 1);  p1 += __shfl_xor(p1, 2);  p1 += __shfl_xor(p1, 4);
    p1 += __shfl_xor(p1, 8);  p1 += __shfl_xor(p1, 16); p1 += __shfl_xor(p1, 32);
    if (ln == 0) {
      out[0] = p0 + b_out[0];
      out[1] = p1 + b_out[1];
    }
  }
}

extern "C" void kernel_launch(void* const* d_in, const int* in_sizes, int n_in,
                              void* d_out, int out_size, void* d_ws, size_t ws_size,
                              hipStream_t stream) {
  const float* x     = (const float*)d_in[0];
  const float* W_ih  = (const float*)d_in[1];
  const float* W_hh  = (const float*)d_in[2];
  const float* b_ih  = (const float*)d_in[3];
  const float* b_hh  = (const float*)d_in[4];
  const float* W_lin = (const float*)d_in[5];
  const float* b_lin = (const float*)d_in[6];
  const float* W_out = (const float*)d_in[7];
  const float* b_out = (const float*)d_in[8];

  lstm_persist<<<dim3(NBLK), dim3(NTHR), 0, stream>>>(
      x, W_ih, W_hh, b_ih, b_hh, W_lin, b_lin, W_out, b_out,
      (float*)d_out, (float*)d_ws);
}

// Round 4
// 50431.564 us; speedup vs baseline: 1.1300x; 1.1300x over previous
//
#include <hip/hip_runtime.h>

// Persistent-LSTM MI355X — Round 10: R6 minus barriers (pipelined consume).
// R7 (fused words), R8 (burn-spin + lockfree publish), R9 (1024-thr blocks,
// VGPR cap 64 -> weight spill) all regressed; R6's config is restored
// byte-for-byte (256 blk x 512 thr, launch_bounds(512,2), ~104 VGPR,
// s_sleep polls, compact tags, one-shot slice reads).
// R10's single variable: INTRA-BLOCK sync. Both __syncthreads in the step
// loop are removed and replaced by per-slice LDS flags:
//   - wave wv: poll its 32 producer tags (R6 poll, s_sleep) -> one-shot
//     read slice wv -> stage to LDS -> release-store flag[wv]=t.
//   - consume: for s=0..7, acquire-spin flag[s]>=t (LDS, broadcast, cheap),
//     then ds_read chunk s + FMA. Early slices' read+FMA overlap late
//     slices' detection; no wait-all convoy.
//   - publish: h store -> own-wave vmcnt(0) drain -> LDS pub counter; the
//     8th wave of the step stores the block tag (s_sleep polls unchanged).
// Safety (tag-chain invariant, no barriers needed):
//   * Overwriting LDS row t&1 at step t: any wave stages only after seeing
//     ALL tags >= t >= t-1; my block's tag t-1 required pub==8(t-1), i.e.
//     every wave of MY block published step t-2, hence finished its
//     step-(t-2) reads of row t&1. WAR-safe.
//   * flag[s] at my step-t spin can be at most t+1 (t+2 would require my
//     own step-t publish), and t+1 targets the OTHER row. Safe.
//   * Tag t+1 is stored only after pub==8t+8 -> all 8 h-stores of step t
//     drained (each wave ran its own vmcnt(0) before incrementing pub).
//     Same release semantics as R6's barrier + tid0 store.
// 0xAA ws poison is negative as signed tag -> inert (R3-R6 validated).

#define H      2048
#define TSTEPS 8192
#define FEAT   128
#define NBLK   256
#define NTHR   512

typedef float vf4 __attribute__((ext_vector_type(4)));
typedef float vf2 __attribute__((ext_vector_type(2)));
typedef unsigned long long u64;
typedef unsigned int u32;

__device__ __forceinline__ float sigm(float xv) {
  return __builtin_amdgcn_rcpf(1.0f + __expf(-xv));
}
__device__ __forceinline__ float tanh_(float xv) {
  return 1.0f - 2.0f * __builtin_amdgcn_rcpf(__expf(2.0f * xv) + 1.0f);
}

__device__ __forceinline__ u64 aload64(const u64* p) {
  return __hip_atomic_load(p, __ATOMIC_RELAXED, __HIP_MEMORY_SCOPE_AGENT);
}
__device__ __forceinline__ u32 aload32(const u32* p) {
  return __hip_atomic_load(p, __ATOMIC_RELAXED, __HIP_MEMORY_SCOPE_AGENT);
}
__device__ __forceinline__ void astoref(float* p, float v) {
  __hip_atomic_store(p, v, __ATOMIC_RELAXED, __HIP_MEMORY_SCOPE_AGENT);
}
__device__ __forceinline__ void astoreu(u32* p, u32 v) {
  __hip_atomic_store(p, v, __ATOMIC_RELAXED, __HIP_MEMORY_SCOPE_AGENT);
}

#define DECLG(g) vf4 w##g##_0, w##g##_1, w##g##_2, w##g##_3, \
                     w##g##_4, w##g##_5, w##g##_6, w##g##_7; \
                 vf2 wih##g; float bias##g; float acc##g;

#define LOADG(g) { \
  const int row_ = (g) * H + j; \
  const float* wr_ = W_hh + (long)row_ * H; \
  w##g##_0 = *(const vf4*)(wr_ + 4*(ln      )); \
  w##g##_1 = *(const vf4*)(wr_ + 4*(ln +  64)); \
  w##g##_2 = *(const vf4*)(wr_ + 4*(ln + 128)); \
  w##g##_3 = *(const vf4*)(wr_ + 4*(ln + 192)); \
  w##g##_4 = *(const vf4*)(wr_ + 4*(ln + 256)); \
  w##g##_5 = *(const vf4*)(wr_ + 4*(ln + 320)); \
  w##g##_6 = *(const vf4*)(wr_ + 4*(ln + 384)); \
  w##g##_7 = *(const vf4*)(wr_ + 4*(ln + 448)); \
  wih##g  = *(const vf2*)(W_ih + (long)row_ * FEAT + 2*ln); \
  bias##g = b_ih[row_] + b_hh[row_]; }

// Opaque pin: weights become non-rematerializable (cannot re-sink into loop).
#define PIN(g) asm volatile("" : \
  "+v"(w##g##_0), "+v"(w##g##_1), "+v"(w##g##_2), "+v"(w##g##_3), \
  "+v"(w##g##_4), "+v"(w##g##_5), "+v"(w##g##_6), "+v"(w##g##_7), \
  "+v"(wih##g), "+v"(bias##g));

#define LDSREAD(k, ldsrow) \
  const vf4 hv##k = *(const vf4*)&(ldsrow)[4*(ln + 64*(k))];

#define FMA_G(g, c) \
  acc##g = __builtin_fmaf(w##g##_##c.x, h4_.x, acc##g); \
  acc##g = __builtin_fmaf(w##g##_##c.y, h4_.y, acc##g); \
  acc##g = __builtin_fmaf(w##g##_##c.z, h4_.z, acc##g); \
  acc##g = __builtin_fmaf(w##g##_##c.w, h4_.w, acc##g);

#define FMA_C(c) { const vf4 h4_ = hv##c; \
  FMA_G(0, c) FMA_G(1, c) FMA_G(2, c) FMA_G(3, c) }

#define REDUCE(g) { float a_ = acc##g; \
  a_ += __shfl_xor(a_, 1);  a_ += __shfl_xor(a_, 2);  a_ += __shfl_xor(a_, 4); \
  a_ += __shfl_xor(a_, 8);  a_ += __shfl_xor(a_, 16); a_ += __shfl_xor(a_, 32); \
  acc##g = a_ + bias##g; }

// Acquire-spin on an LDS slice flag (same addr all lanes -> broadcast).
// Acquire ordering keeps the following ds_reads from hoisting above it.
#define SPIN(s) \
  while (__hip_atomic_load(&flag[s], __ATOMIC_ACQUIRE, \
                           __HIP_MEMORY_SCOPE_WORKGROUP) < t) {} \
  asm volatile("" ::: "memory");

__global__ __launch_bounds__(NTHR, 2)
void lstm_persist(const float* __restrict__ x,
                  const float* __restrict__ W_ih,
                  const float* __restrict__ W_hh,
                  const float* __restrict__ b_ih,
                  const float* __restrict__ b_hh,
                  const float* __restrict__ W_lin,
                  const float* __restrict__ b_lin,
                  const float* __restrict__ W_out,
                  const float* __restrict__ b_out,
                  float* __restrict__ out,
                  float* __restrict__ ws)
{
  const int tid = threadIdx.x;
  const int b   = blockIdx.x;
  const int wv  = tid >> 6;
  const int ln  = tid & 63;

  float* hbuf0 = ws;            // [2048] h for even t
  float* hbuf1 = ws + H;        // [2048] h for odd t; reused for ylin
  u32*   slots = (u32*)(ws + 2 * H);   // [256] per-block step counters, 1KB

  __shared__ __align__(16) float h_lds[2][H];
  __shared__ int flag[8];       // flag[s]=t: slice s of row t&1 staged
  __shared__ int pub_cnt;       // monotonic: 8 increments per step

  // h_0 = 0: zero parity-0 LDS row (512 threads x 16B)
  *(vf4*)&h_lds[0][4 * tid] = (vf4)(0.0f);
  if (tid < 8) flag[tid] = 0;
  if (tid == 0) pub_cnt = 0;

  // ---- persistent weights: load then pin ----
  const int j = b * 8 + wv;
  DECLG(0) DECLG(1) DECLG(2) DECLG(3)
  LOADG(0) LOADG(1) LOADG(2) LOADG(3)
  PIN(0) PIN(1) PIN(2) PIN(3)

  __syncthreads();   // only barrier before the head phases

  float cst = 0.0f;

  #pragma unroll 1
  for (int t = 0; t < TSTEPS; ++t) {
    const vf2 xr = *(const vf2*)(x + (long)t * FEAT + 2 * ln);
    float* ldsrow = h_lds[t & 1];

    if (t > 0) {
      // gate poll: this wave's 32 producer blocks (R6 poll, s_sleep backoff)
      const u32* sp = slots + wv * 32 + (ln & 31);
      int v = (ln < 32) ? (int)aload32(sp) : 0x7fffffff;
      while (!__all(v >= t)) {
        __builtin_amdgcn_s_sleep(1);
        if ((ln < 32) && (v < t)) v = (int)aload32(sp);
      }
      // one-shot read of slice wv (4 floats/lane) + stage to LDS
      const int base = wv * 256 + 4 * ln;
      const float* hsrc = (t & 1) ? hbuf1 : hbuf0;
      const u64* hp = (const u64*)(hsrc + base);
      const u64 d0 = aload64(hp);
      const u64 d1 = aload64(hp + 1);
      vf4 hv;
      hv.x = __uint_as_float((u32)d0);
      hv.y = __uint_as_float((u32)(d0 >> 32));
      hv.z = __uint_as_float((u32)d1);
      hv.w = __uint_as_float((u32)(d1 >> 32));
      *(vf4*)&ldsrow[base] = hv;
      // release: staging write visible to the block before flag flips
      if (ln == 0)
        __hip_atomic_store(&flag[wv], t, __ATOMIC_RELEASE,
                           __HIP_MEMORY_SCOPE_WORKGROUP);
      asm volatile("" ::: "memory");
    }

    acc0 = wih0.x * xr.x + wih0.y * xr.y;
    acc1 = wih1.x * xr.x + wih1.y * xr.y;
    acc2 = wih2.x * xr.x + wih2.y * xr.y;
    acc3 = wih3.x * xr.x + wih3.y * xr.y;

    // pipelined consume: spin-per-slice, FMA overlaps later arrivals
    SPIN(0) LDSREAD(0, ldsrow) FMA_C(0)
    SPIN(1) LDSREAD(1, ldsrow) FMA_C(1)
    SPIN(2) LDSREAD(2, ldsrow) FMA_C(2)
    SPIN(3) LDSREAD(3, ldsrow) FMA_C(3)
    SPIN(4) LDSREAD(4, ldsrow) FMA_C(4)
    SPIN(5) LDSREAD(5, ldsrow) FMA_C(5)
    SPIN(6) LDSREAD(6, ldsrow) FMA_C(6)
    SPIN(7) LDSREAD(7, ldsrow) FMA_C(7)

    REDUCE(0) REDUCE(1) REDUCE(2) REDUCE(3)

    // gate order [i, f, g, o]
    const float iv = sigm(acc0);
    const float fv = sigm(acc1);
    const float gv = tanh_(acc2);
    const float ov = sigm(acc3);
    cst = fv * cst + iv * gv;
    const float hval = ov * tanh_(cst);

    // publish h_{t+1}: store -> own-wave ack drain -> LDS pub counter;
    // the 8th wave of this step stores the compact block tag.
    if (ln == 0)
      astoref((((t + 1) & 1) ? hbuf1 : hbuf0) + j, hval);
    asm volatile("s_waitcnt vmcnt(0)" ::: "memory");
    if (ln == 0) {
      const int old = atomicAdd(&pub_cnt, 1);
      if (old == 8 * t + 7)
        astoreu(slots + b, (u32)(t + 1));
    }
  }

  // ---- head phase 1: ylin[j] = b_lin[j] + dot(W_lin[j,:], h_final) ----
  // h_final = h_8192, parity 0; all tags reach TSTEPS after the loop.
  // Row-0 WAR: tags >= TSTEPS implies every wave finished step-8190 reads.
  {
    float* ldsrow = h_lds[0];
    const u32* sp = slots + wv * 32 + (ln & 31);
    int v = (ln < 32) ? (int)aload32(sp) : 0x7fffffff;
    while (!__all(v >= TSTEPS)) {
      __builtin_amdgcn_s_sleep(1);
      if ((ln < 32) && (v < TSTEPS)) v = (int)aload32(sp);
    }
    const int base = wv * 256 + 4 * ln;
    const u64* hp = (const u64*)(hbuf0 + base);
    const u64 d0 = aload64(hp);
    const u64 d1 = aload64(hp + 1);
    vf4 hv;
    hv.x = __uint_as_float((u32)d0);
    hv.y = __uint_as_float((u32)(d0 >> 32));
    hv.z = __uint_as_float((u32)d1);
    hv.w = __uint_as_float((u32)(d1 >> 32));
    *(vf4*)&ldsrow[base] = hv;
    __syncthreads();   // off the hot path: simple convergence for the head

    float a0 = 0.0f;
    const float* wl = W_lin + (long)j * H;
    #pragma unroll
    for (int k = 0; k < 8; ++k) {
      const vf4 h4 = *(const vf4*)&ldsrow[4 * (ln + 64 * k)];
      const vf4 u  = *(const vf4*)(wl + 4 * (ln + 64 * k));
      a0 += u.x * h4.x + u.y * h4.y + u.z * h4.z + u.w * h4.w;
    }
    a0 += __shfl_xor(a0, 1);  a0 += __shfl_xor(a0, 2);  a0 += __shfl_xor(a0, 4);
    a0 += __shfl_xor(a0, 8);  a0 += __shfl_xor(a0, 16); a0 += __shfl_xor(a0, 32);

    if (ln == 0)
      astoref(hbuf1 + j, a0 + b_lin[j]);   // ylin lives in hbuf1 (safe: all
                                           // blocks are past reading h_8191)
    __syncthreads();   // drains vmcnt -> ylin visible before tag below
    if (tid == 0)
      astoreu(slots + b, (u32)(TSTEPS + 1));
  }

  // ---- head phase 2: y = ylin @ W_out.T + b_out (block 0, wave 0) ----
  if (b == 0 && wv == 0) {
    // poll all 256 slots: lane ln covers slots 4ln..4ln+3
    const u32* sp = slots + 4 * ln;
    int v0 = (int)aload32(sp + 0), v1 = (int)aload32(sp + 1);
    int v2 = (int)aload32(sp + 2), v3 = (int)aload32(sp + 3);
    const int tgt = TSTEPS + 1;
    while (!__all((v0 >= tgt) & (v1 >= tgt) & (v2 >= tgt) & (v3 >= tgt))) {
      __builtin_amdgcn_s_sleep(1);
      if (v0 < tgt) v0 = (int)aload32(sp + 0);
      if (v1 < tgt) v1 = (int)aload32(sp + 1);
      if (v2 < tgt) v2 = (int)aload32(sp + 2);
      if (v3 < tgt) v3 = (int)aload32(sp + 3);
    }
    float p0 = 0.0f, p1 = 0.0f;
    #pragma unroll
    for (int k = 0; k < 16; ++k) {
      const u64 d  = aload64((const u64*)hbuf1 + ln + 64 * k);
      const int c  = 2 * (ln + 64 * k);
      const float ylo = __uint_as_float((u32)d);
      const float yhi = __uint_as_float((u32)(d >> 32));
      p0 = __builtin_fmaf(W_out[c],         ylo, p0);
      p0 = __builtin_fmaf(W_out[c + 1],     yhi, p0);
      p1 = __builtin_fmaf(W_out[H + c],     ylo, p1);
      p1 = __builtin_fmaf(W_out[H + c + 1], yhi, p1);
    }
    p0 += __shfl_xor(p0, 1);  p0 += __shfl_xor(p0, 2);  p0 += __shfl_xor(p0, 4);
    p0 += __shfl_xor(p0, 8);  p0 += __shfl_xor(p0, 16); p0 += __shfl_xor(p0, 32);
    p1 += __shfl_xor(p1, 1);  p1 += __shfl_xor(p1, 2);  p1 += __shfl_xor(p1, 4);
    p1 += __shfl_xor(p1, 8);  p1 += __shfl_xor(p1, 16); p1 += __shfl_xor(p1, 32);
    if (ln == 0) {
      out[0] = p0 + b_out[0];
      out[1] = p1 + b_out[1];
    }
  }
}

extern "C" void kernel_launch(void* const* d_in, const int* in_sizes, int n_in,
                              void* d_out, int out_size, void* d_ws, size_t ws_size,
                              hipStream_t stream) {
  const float* x     = (const float*)d_in[0];
  const float* W_ih  = (const float*)d_in[1];
  const float* W_hh  = (const float*)d_in[2];
  const float* b_ih  = (const float*)d_in[3];
  const float* b_hh  = (const float*)d_in[4];
  const float* W_lin = (const float*)d_in[5];
  const float* b_lin = (const float*)d_in[6];
  const float* W_out = (const float*)d_in[7];
  const float* b_out = (const float*)d_in[8];

  lstm_persist<<<dim3(NBLK), dim3(NTHR), 0, stream>>>(
      x, W_ih, W_hh, b_ih, b_hh, W_lin, b_lin, W_out, b_out,
      (float*)d_out, (float*)d_ws);
}

// Round 5
// 32232.074 us; speedup vs baseline: 1.7680x; 1.5646x over previous
//
#include <hip/hip_runtime.h>

// Persistent-LSTM MI355X — Round 11: R6 restored byte-for-byte + ONE change:
// 2-deep software-pipelined tag poll.
// Session evidence: every variant that removed the producer-side barrier
// (R7 fused words, R8 lockfree publish, R10 per-slice flags) cost +2us/step;
// R9's geometry change hit a VGPR cap and spilled weights. R6's structure
// (256x512, both barriers, compact tags, s_sleep polls, one-shot reads) is
// a sharp local optimum — restored exactly.
// R11's single variable: the gate poll was a DEPENDENT load chain
// (load ~550cy -> check -> sleep -> load), so a newly-visible tag waited
// ~half a round + flight. Now two tag loads are kept in flight; each round
// checks the older while the newer flies: round time ~(L+c)/2 ~ 320cy.
// Ordering unchanged: the data read still issues only after a COMPLETED
// tag read >= t (monotonic tags; producer drains h-stores before tag),
// so freshness of the one-shot h read is preserved exactly as in R6.
//
// 256 blocks x 512 threads, 1 block/CU, all co-resident -> spin-poll
// deadlock-free (slots are monotonic). Block b owns units [8b,8b+8); wave
// wv computes unit j=8b+wv; lane ln owns h-chunks {ln+64k} for FMA and
// contiguous 4 floats for staging. 0xAA ws poison is negative as signed
// tag -> inert (R3-R6 validated).

#define H      2048
#define TSTEPS 8192
#define FEAT   128
#define NBLK   256
#define NTHR   512

typedef float vf4 __attribute__((ext_vector_type(4)));
typedef float vf2 __attribute__((ext_vector_type(2)));
typedef unsigned long long u64;
typedef unsigned int u32;

__device__ __forceinline__ float sigm(float xv) {
  return __builtin_amdgcn_rcpf(1.0f + __expf(-xv));
}
__device__ __forceinline__ float tanh_(float xv) {
  return 1.0f - 2.0f * __builtin_amdgcn_rcpf(__expf(2.0f * xv) + 1.0f);
}

__device__ __forceinline__ u64 aload64(const u64* p) {
  return __hip_atomic_load(p, __ATOMIC_RELAXED, __HIP_MEMORY_SCOPE_AGENT);
}
__device__ __forceinline__ u32 aload32(const u32* p) {
  return __hip_atomic_load(p, __ATOMIC_RELAXED, __HIP_MEMORY_SCOPE_AGENT);
}
__device__ __forceinline__ void astoref(float* p, float v) {
  __hip_atomic_store(p, v, __ATOMIC_RELAXED, __HIP_MEMORY_SCOPE_AGENT);
}
__device__ __forceinline__ void astoreu(u32* p, u32 v) {
  __hip_atomic_store(p, v, __ATOMIC_RELAXED, __HIP_MEMORY_SCOPE_AGENT);
}

#define DECLG(g) vf4 w##g##_0, w##g##_1, w##g##_2, w##g##_3, \
                     w##g##_4, w##g##_5, w##g##_6, w##g##_7; \
                 vf2 wih##g; float bias##g; float acc##g;

#define LOADG(g) { \
  const int row_ = (g) * H + j; \
  const float* wr_ = W_hh + (long)row_ * H; \
  w##g##_0 = *(const vf4*)(wr_ + 4*(ln      )); \
  w##g##_1 = *(const vf4*)(wr_ + 4*(ln +  64)); \
  w##g##_2 = *(const vf4*)(wr_ + 4*(ln + 128)); \
  w##g##_3 = *(const vf4*)(wr_ + 4*(ln + 192)); \
  w##g##_4 = *(const vf4*)(wr_ + 4*(ln + 256)); \
  w##g##_5 = *(const vf4*)(wr_ + 4*(ln + 320)); \
  w##g##_6 = *(const vf4*)(wr_ + 4*(ln + 384)); \
  w##g##_7 = *(const vf4*)(wr_ + 4*(ln + 448)); \
  wih##g  = *(const vf2*)(W_ih + (long)row_ * FEAT + 2*ln); \
  bias##g = b_ih[row_] + b_hh[row_]; }

// Opaque pin: weights become non-rematerializable (cannot re-sink into loop).
#define PIN(g) asm volatile("" : \
  "+v"(w##g##_0), "+v"(w##g##_1), "+v"(w##g##_2), "+v"(w##g##_3), \
  "+v"(w##g##_4), "+v"(w##g##_5), "+v"(w##g##_6), "+v"(w##g##_7), \
  "+v"(wih##g), "+v"(bias##g));

#define LDSREAD(k, ldsrow) \
  const vf4 hv##k = *(const vf4*)&(ldsrow)[4*(ln + 64*(k))];

#define FMA_G(g, c) \
  acc##g = __builtin_fmaf(w##g##_##c.x, h4_.x, acc##g); \
  acc##g = __builtin_fmaf(w##g##_##c.y, h4_.y, acc##g); \
  acc##g = __builtin_fmaf(w##g##_##c.z, h4_.z, acc##g); \
  acc##g = __builtin_fmaf(w##g##_##c.w, h4_.w, acc##g);

#define FMA_C(c) { const vf4 h4_ = hv##c; \
  FMA_G(0, c) FMA_G(1, c) FMA_G(2, c) FMA_G(3, c) }

#define REDUCE(g) { float a_ = acc##g; \
  a_ += __shfl_xor(a_, 1);  a_ += __shfl_xor(a_, 2);  a_ += __shfl_xor(a_, 4); \
  a_ += __shfl_xor(a_, 8);  a_ += __shfl_xor(a_, 16); a_ += __shfl_xor(a_, 32); \
  acc##g = a_ + bias##g; }

// Wave wv: (1) poll the 32 slot-counters of its slice's producer blocks
// (2 cache lines; lanes 0..31, one u32 each) with TWO loads in flight —
// check the older value while the newer flies (round ~(L+c)/2 vs L+c);
// (2) after a completed read passes, one-shot read the 256-float h-slice
// (4 floats/lane via 2 u64 loads); (3) deposit into LDS.
__device__ __forceinline__ void poll_and_stage(const u32* __restrict__ slots,
                                               const float* __restrict__ hsrc,
                                               int tgt,
                                               float* __restrict__ ldsrow,
                                               int wv, int ln) {
  const u32* sp = slots + wv * 32 + (ln & 31);
  const bool act = (ln < 32);
  int v0 = act ? (int)aload32(sp) : 0x7fffffff;
  int v1 = act ? (int)aload32(sp) : 0x7fffffff;
  while (!__all(v0 >= tgt)) {
    __builtin_amdgcn_s_sleep(1);
    v0 = v1;                                    // check last round's load...
    v1 = act ? (int)aload32(sp) : 0x7fffffff;   // ...while this one flies
  }
  const int base = wv * 256 + 4 * ln;
  const u64* hp = (const u64*)(hsrc + base);
  const u64 d0 = aload64(hp);
  const u64 d1 = aload64(hp + 1);
  vf4 hv;
  hv.x = __uint_as_float((u32)d0);
  hv.y = __uint_as_float((u32)(d0 >> 32));
  hv.z = __uint_as_float((u32)d1);
  hv.w = __uint_as_float((u32)(d1 >> 32));
  *(vf4*)&ldsrow[base] = hv;
}

__global__ __launch_bounds__(NTHR, 2)
void lstm_persist(const float* __restrict__ x,
                  const float* __restrict__ W_ih,
                  const float* __restrict__ W_hh,
                  const float* __restrict__ b_ih,
                  const float* __restrict__ b_hh,
                  const float* __restrict__ W_lin,
                  const float* __restrict__ b_lin,
                  const float* __restrict__ W_out,
                  const float* __restrict__ b_out,
                  float* __restrict__ out,
                  float* __restrict__ ws)
{
  const int tid = threadIdx.x;
  const int b   = blockIdx.x;
  const int wv  = tid >> 6;
  const int ln  = tid & 63;

  float* hbuf0 = ws;            // [2048] h for even t
  float* hbuf1 = ws + H;        // [2048] h for odd t; reused for ylin
  u32*   slots = (u32*)(ws + 2 * H);   // [256] per-block step counters, 1KB

  __shared__ __align__(16) float h_lds[2][H];

  // h_0 = 0: zero parity-0 LDS row (512 threads x 16B)
  *(vf4*)&h_lds[0][4 * tid] = (vf4)(0.0f);

  // ---- persistent weights: load then pin ----
  const int j = b * 8 + wv;
  DECLG(0) DECLG(1) DECLG(2) DECLG(3)
  LOADG(0) LOADG(1) LOADG(2) LOADG(3)
  PIN(0) PIN(1) PIN(2) PIN(3)

  __syncthreads();

  float cst = 0.0f;

  #pragma unroll 1
  for (int t = 0; t < TSTEPS; ++t) {
    const vf2 xr = *(const vf2*)(x + (long)t * FEAT + 2 * ln);
    float* ldsrow = h_lds[t & 1];

    if (t > 0)
      poll_and_stage(slots, (t & 1) ? hbuf1 : hbuf0, t, ldsrow, wv, ln);
    __syncthreads();

    LDSREAD(0, ldsrow) LDSREAD(1, ldsrow) LDSREAD(2, ldsrow) LDSREAD(3, ldsrow)
    LDSREAD(4, ldsrow) LDSREAD(5, ldsrow) LDSREAD(6, ldsrow) LDSREAD(7, ldsrow)

    acc0 = wih0.x * xr.x + wih0.y * xr.y;
    acc1 = wih1.x * xr.x + wih1.y * xr.y;
    acc2 = wih2.x * xr.x + wih2.y * xr.y;
    acc3 = wih3.x * xr.x + wih3.y * xr.y;

    FMA_C(0) FMA_C(1) FMA_C(2) FMA_C(3)
    FMA_C(4) FMA_C(5) FMA_C(6) FMA_C(7)

    REDUCE(0) REDUCE(1) REDUCE(2) REDUCE(3)

    // gate order [i, f, g, o]
    const float iv = sigm(acc0);
    const float fv = sigm(acc1);
    const float gv = tanh_(acc2);
    const float ov = sigm(acc3);
    cst = fv * cst + iv * gv;
    const float hval = ov * tanh_(cst);

    // publish h_{t+1}: 8 plain stores per block (one line)
    if (ln == 0)
      astoref((((t + 1) & 1) ? hbuf1 : hbuf0) + j, hval);

    // syncthreads drains vmcnt(0) per wave before s_barrier -> all 8 h
    // stores of this block are visible BEFORE the tag store below.
    __syncthreads();
    if (tid == 0)
      astoreu(slots + b, (u32)(t + 1));
  }

  // ---- head phase 1: ylin[j] = b_lin[j] + dot(W_lin[j,:], h_final) ----
  // h_final = h_8192, parity 0; all slots reach TSTEPS after the loop.
  {
    float* ldsrow = h_lds[0];
    poll_and_stage(slots, hbuf0, TSTEPS, ldsrow, wv, ln);
    __syncthreads();

    float a0 = 0.0f;
    const float* wl = W_lin + (long)j * H;
    #pragma unroll
    for (int k = 0; k < 8; ++k) {
      const vf4 h4 = *(const vf4*)&ldsrow[4 * (ln + 64 * k)];
      const vf4 u  = *(const vf4*)(wl + 4 * (ln + 64 * k));
      a0 += u.x * h4.x + u.y * h4.y + u.z * h4.z + u.w * h4.w;
    }
    a0 += __shfl_xor(a0, 1);  a0 += __shfl_xor(a0, 2);  a0 += __shfl_xor(a0, 4);
    a0 += __shfl_xor(a0, 8);  a0 += __shfl_xor(a0, 16); a0 += __shfl_xor(a0, 32);

    if (ln == 0)
      astoref(hbuf1 + j, a0 + b_lin[j]);   // ylin lives in hbuf1 (safe: all
                                           // blocks are past reading h_8191)
    __syncthreads();
    if (tid == 0)
      astoreu(slots + b, (u32)(TSTEPS + 1));
  }

  // ---- head phase 2: y = ylin @ W_out.T + b_out (block 0, wave 0) ----
  if (b == 0 && wv == 0) {
    // poll all 256 slots: lane ln covers slots 4ln..4ln+3
    const u32* sp = slots + 4 * ln;
    int v0 = (int)aload32(sp + 0), v1 = (int)aload32(sp + 1);
    int v2 = (int)aload32(sp + 2), v3 = (int)aload32(sp + 3);
    const int tgt = TSTEPS + 1;
    while (!__all((v0 >= tgt) & (v1 >= tgt) & (v2 >= tgt) & (v3 >= tgt))) {
      __builtin_amdgcn_s_sleep(1);
      if (v0 < tgt) v0 = (int)aload32(sp + 0);
      if (v1 < tgt) v1 = (int)aload32(sp + 1);
      if (v2 < tgt) v2 = (int)aload32(sp + 2);
      if (v3 < tgt) v3 = (int)aload32(sp + 3);
    }
    float p0 = 0.0f, p1 = 0.0f;
    #pragma unroll
    for (int k = 0; k < 16; ++k) {
      const u64 d  = aload64((const u64*)hbuf1 + ln + 64 * k);
      const int c  = 2 * (ln + 64 * k);
      const float ylo = __uint_as_float((u32)d);
      const float yhi = __uint_as_float((u32)(d >> 32));
      p0 = __builtin_fmaf(W_out[c],         ylo, p0);
      p0 = __builtin_fmaf(W_out[c + 1],     yhi, p0);
      p1 = __builtin_fmaf(W_out[H + c],     ylo, p1);
      p1 = __builtin_fmaf(W_out[H + c + 1], yhi, p1);
    }
    p0 += __shfl_xor(p0, 1);  p0 += __shfl_xor(p0, 2);  p0 += __shfl_xor(p0, 4);
    p0 += __shfl_xor(p0, 8);  p0 += __shfl_xor(p0, 16); p0 += __shfl_xor(p0, 32);
    p1 += __shfl_xor(p1, 1);  p1 += __shfl_xor(p1, 2);  p1 += __shfl_xor(p1, 4);
    p1 += __shfl_xor(p1, 8);  p1 += __shfl_xor(p1, 16); p1 += __shfl_xor(p1, 32);
    if (ln == 0) {
      out[0] = p0 + b_out[0];
      out[1] = p1 + b_out[1];
    }
  }
}

extern "C" void kernel_launch(void* const* d_in, const int* in_sizes, int n_in,
                              void* d_out, int out_size, void* d_ws, size_t ws_size,
                              hipStream_t stream) {
  const float* x     = (const float*)d_in[0];
  const float* W_ih  = (const float*)d_in[1];
  const float* W_hh  = (const float*)d_in[2];
  const float* b_ih  = (const float*)d_in[3];
  const float* b_hh  = (const float*)d_in[4];
  const float* W_lin = (const float*)d_in[5];
  const float* b_lin = (const float*)d_in[6];
  const float* W_out = (const float*)d_in[7];
  const float* b_out = (const float*)d_in[8];

  lstm_persist<<<dim3(NBLK), dim3(NTHR), 0, stream>>>(
      x, W_ih, W_hh, b_ih, b_hh, W_lin, b_lin, W_out, b_out,
      (float*)d_out, (float*)d_ws);
}